// Round 8
// baseline (336.858 us; speedup 1.0000x reference)
//
#include <hip/hip_runtime.h>
#include <hip/hip_fp16.h>
#include <math.h>

// GraphSAGE 2-layer, N=100000 nodes, E=3200000 edges
// IN=128, H1=32, H2=20, NCLS=10
// Aggregate in OUTPUT feature space; CSR-by-dst via 2-level bucketing;
// fp16 tables with 64B rows. Agg kernels: one wave64 per node, 8 slots x
// 8 lanes, uint2 (8B) per lane -> 1 gather instruction covers 8 edges;
// 4-deep unroll = 32 edges in flight per wave.

#define BSHIFT 7
#define BS_NODES 128          // nodes per bucket
#define PART_TILE 4096        // edges per k_part block

__global__ __launch_bounds__(256) void k_lin1(
    const float* __restrict__ x, const float* __restrict__ W1l,
    const float* __restrict__ W1r, __half* __restrict__ y1,
    float* __restrict__ r1, int n_nodes)
{
    int n = blockIdx.x * 256 + threadIdx.x;
    if (n >= n_nodes) return;
    float accL[32], accR[32];
#pragma unroll
    for (int j = 0; j < 32; ++j) { accL[j] = 0.f; accR[j] = 0.f; }
    const float4* x4 = reinterpret_cast<const float4*>(x) + (size_t)n * 32;
    for (int k4 = 0; k4 < 32; ++k4) {
        float4 xv = x4[k4];
        const float* wl = W1l + k4 * 4 * 32;   // wave-uniform -> scalar loads
        const float* wr = W1r + k4 * 4 * 32;
#pragma unroll
        for (int j = 0; j < 32; ++j) {
            float a = accL[j];
            a = fmaf(xv.x, wl[j],      a);
            a = fmaf(xv.y, wl[32 + j], a);
            a = fmaf(xv.z, wl[64 + j], a);
            a = fmaf(xv.w, wl[96 + j], a);
            accL[j] = a;
            float b = accR[j];
            b = fmaf(xv.x, wr[j],      b);
            b = fmaf(xv.y, wr[32 + j], b);
            b = fmaf(xv.z, wr[64 + j], b);
            b = fmaf(xv.w, wr[96 + j], b);
            accR[j] = b;
        }
    }
    unsigned upk[16];
#pragma unroll
    for (int q = 0; q < 16; ++q) {
        __half2 h = __floats2half2_rn(accL[2*q], accL[2*q+1]);
        upk[q] = *reinterpret_cast<unsigned*>(&h);
    }
    uint4* yo = reinterpret_cast<uint4*>(y1 + (size_t)n * 32);
#pragma unroll
    for (int q = 0; q < 4; ++q)
        yo[q] = make_uint4(upk[4*q], upk[4*q+1], upk[4*q+2], upk[4*q+3]);
    float4* ro = reinterpret_cast<float4*>(r1 + (size_t)n * 32);
#pragma unroll
    for (int q = 0; q < 8; ++q)
        ro[q] = make_float4(accR[q*4], accR[q*4+1], accR[q*4+2], accR[q*4+3]);
}

// ---- CSR build, stage 0 ----
__global__ __launch_bounds__(256) void k_binit(
    int* __restrict__ bcursor, int nb, int capb)
{
    int i = blockIdx.x * 256 + threadIdx.x;
    if (i < nb) bcursor[i] = i * capb;
}

// ---- stage 1: partition edges into per-bucket regions ----
__global__ __launch_bounds__(256) void k_part(
    const int* __restrict__ src, const int* __restrict__ dst,
    int* __restrict__ bcursor, int* __restrict__ pairs,
    int n_edges, int nb)
{
    __shared__ int cnt[1024];
    __shared__ int bbase_l[1024];
    int tid = threadIdx.x;
    int ebeg = blockIdx.x * PART_TILE;
    int eend = ebeg + PART_TILE; if (eend > n_edges) eend = n_edges;
    for (int i = tid; i < nb; i += 256) cnt[i] = 0;
    __syncthreads();
    for (int e = ebeg + tid; e < eend; e += 256)
        atomicAdd(&cnt[dst[e] >> BSHIFT], 1);
    __syncthreads();
    for (int i = tid; i < nb; i += 256) {
        int c = cnt[i];
        if (c > 0) bbase_l[i] = atomicAdd(&bcursor[i], c);
    }
    __syncthreads();
    for (int e = ebeg + tid; e < eend; e += 256) {
        int d = dst[e];
        int b = d >> BSHIFT;
        int slot = atomicSub(&cnt[b], 1) - 1;     // countdown ticket
        pairs[(size_t)bbase_l[b] + slot] = (src[e] << BSHIFT) | (d & (BS_NODES - 1));
    }
}

// ---- stage 2: scan bucket counts ----
__global__ __launch_bounds__(1024) void k_bscan(
    const int* __restrict__ bcursor, int* __restrict__ bbase,
    int* __restrict__ row_ptr, int nb, int capb, int n_nodes)
{
    __shared__ int sc[1024];
    int t = threadIdx.x;
    int c = (t < nb) ? (bcursor[t] - t * capb) : 0;
    sc[t] = c;
    __syncthreads();
    for (int off = 1; off < 1024; off <<= 1) {
        int v = (t >= off) ? sc[t - off] : 0;
        __syncthreads();
        sc[t] += v;
        __syncthreads();
    }
    if (t < nb) bbase[t] = sc[t] - c;   // exclusive
    if (t == 1023) row_ptr[n_nodes] = sc[t];
}

// ---- stage 3: per-bucket fill of row_ptr + eid ----
__global__ __launch_bounds__(256) void k_bfill(
    const int* __restrict__ pairs, const int* __restrict__ bcursor,
    const int* __restrict__ bbase, int* __restrict__ row_ptr,
    int* __restrict__ eid, int capb, int n_nodes)
{
    __shared__ int cnt128[BS_NODES];
    __shared__ int sc[BS_NODES];
    __shared__ int cur[BS_NODES];
    int b = blockIdx.x;
    int t = threadIdx.x;
    int lo = b * BS_NODES;
    size_t pbeg = (size_t)b * capb;
    int cntE = bcursor[b] - b * capb;
    int base = bbase[b];
    if (t < BS_NODES) cnt128[t] = 0;
    __syncthreads();
    for (int i = t; i < cntE; i += 256)
        atomicAdd(&cnt128[pairs[pbeg + i] & (BS_NODES - 1)], 1);
    __syncthreads();
    int myc = 0;
    if (t < BS_NODES) { myc = cnt128[t]; sc[t] = myc; }
    __syncthreads();
    for (int off = 1; off < BS_NODES; off <<= 1) {
        int v = (t >= off && t < BS_NODES) ? sc[t - off] : 0;
        __syncthreads();
        if (t < BS_NODES) sc[t] += v;
        __syncthreads();
    }
    if (t < BS_NODES) {
        int excl = sc[t] - myc;
        cur[t] = excl;
        if (lo + t < n_nodes) row_ptr[lo + t] = base + excl;
    }
    __syncthreads();
    for (int i = t; i < cntE; i += 256) {
        int p = pairs[pbeg + i];
        int pos = atomicAdd(&cur[p & (BS_NODES - 1)], 1);
        eid[(size_t)base + pos] = p >> BSHIFT;
    }
}

__device__ __forceinline__ void acc4(uint2 g, float& x0, float& x1,
                                     float& x2, float& x3)
{
    __half2 p0 = *reinterpret_cast<__half2*>(&g.x);
    __half2 p1 = *reinterpret_cast<__half2*>(&g.y);
    float2 f0 = __half22float2(p0);
    float2 f1 = __half22float2(p1);
    x0 += f0.x; x1 += f0.y; x2 += f1.x; x3 += f1.y;
}

// ---- Layer 1: wave-per-node gather (8 slots x 8B), combine, norm, project ----
__global__ __launch_bounds__(256) void k_agg1(
    const int* __restrict__ row_ptr, const int* __restrict__ eid,
    const __half* __restrict__ y1, const float* __restrict__ r1,
    const float* __restrict__ bias1, const float* __restrict__ W2l,
    const float* __restrict__ W2r,
    __half* __restrict__ z2, float* __restrict__ r2, int n_nodes)
{
    int n = (blockIdx.x * 256 + threadIdx.x) >> 6;
    if (n >= n_nodes) return;
    int lane = threadIdx.x & 63;
    int s = lane >> 3;        // slot: edge within octet
    int q = lane & 7;         // quad: channels 4q..4q+3
    int beg = row_ptr[n], end = row_ptr[n + 1];
    int m = end - beg;
    int K = m >> 3;
    const char* yb = (const char*)y1;
    int boff = q << 3;
    float A0=0,A1=0,A2=0,A3=0, B0=0,B1=0,B2=0,B3=0;
    float C0=0,C1=0,C2=0,C3=0, D0=0,D1=0,D2=0,D3=0;
    int base = beg + s;
    int k = 0;
    for (; k + 4 <= K; k += 4) {
        int e0 = eid[base + 8*k];
        int e1 = eid[base + 8*k + 8];
        int e2 = eid[base + 8*k + 16];
        int e3 = eid[base + 8*k + 24];
        uint2 g0 = *reinterpret_cast<const uint2*>(yb + ((size_t)e0 << 6) + boff);
        uint2 g1 = *reinterpret_cast<const uint2*>(yb + ((size_t)e1 << 6) + boff);
        uint2 g2 = *reinterpret_cast<const uint2*>(yb + ((size_t)e2 << 6) + boff);
        uint2 g3 = *reinterpret_cast<const uint2*>(yb + ((size_t)e3 << 6) + boff);
        acc4(g0, A0, A1, A2, A3);
        acc4(g1, B0, B1, B2, B3);
        acc4(g2, C0, C1, C2, C3);
        acc4(g3, D0, D1, D2, D3);
    }
    for (; k < K; ++k) {
        int e = eid[base + 8*k];
        uint2 g = *reinterpret_cast<const uint2*>(yb + ((size_t)e << 6) + boff);
        acc4(g, A0, A1, A2, A3);
    }
    if (s < (m & 7)) {
        int e = eid[beg + 8*K + s];
        uint2 g = *reinterpret_cast<const uint2*>(yb + ((size_t)e << 6) + boff);
        acc4(g, B0, B1, B2, B3);
    }
    float v0 = (A0 + B0) + (C0 + D0);
    float v1 = (A1 + B1) + (C1 + D1);
    float v2 = (A2 + B2) + (C2 + D2);
    float v3 = (A3 + B3) + (C3 + D3);
    // reduce across slots (channels live per-quad, replicated after this)
#pragma unroll
    for (int off = 8; off < 64; off <<= 1) {
        v0 += __shfl_xor(v0, off, 64);
        v1 += __shfl_xor(v1, off, 64);
        v2 += __shfl_xor(v2, off, 64);
        v3 += __shfl_xor(v3, off, 64);
    }
    float inv = 1.0f / fmaxf((float)m, 1.0f);
    int ch0 = q << 2;
    float4 rs = *reinterpret_cast<const float4*>(r1 + (size_t)n * 32 + ch0);
    float4 bs = *reinterpret_cast<const float4*>(bias1 + ch0);
    float w0 = fmaf(v0, inv, bs.x + rs.x);
    float w1 = fmaf(v1, inv, bs.y + rs.y);
    float w2 = fmaf(v2, inv, bs.z + rs.z);
    float w3 = fmaf(v3, inv, bs.w + rs.w);
    float ss = w0*w0 + w1*w1 + w2*w2 + w3*w3;
#pragma unroll
    for (int off = 1; off < 8; off <<= 1) ss += __shfl_xor(ss, off, 64);
    float innrm = 1.0f / fmaxf(sqrtf(ss), 1e-12f);
    float h0 = fmaxf(w0 * innrm, 0.f);
    float h1 = fmaxf(w1 * innrm, 0.f);
    float h2 = fmaxf(w2 * innrm, 0.f);
    float h3 = fmaxf(w3 * innrm, 0.f);
    // projection: lanes 0..19 -> z2 col lane (W2l); lanes 32..51 -> r2 col lane-32 (W2r)
    bool doL = lane < 20;
    bool doR = (lane >= 32) && (lane < 52);
    const float* Wcol = doR ? (W2r + (lane - 32)) : (W2l + (doL ? lane : 0));
    float acc = 0.f;
#pragma unroll
    for (int ii = 0; ii < 32; ++ii) {
        float hsrc = ((ii & 3) == 0) ? h0 : ((ii & 3) == 1) ? h1
                   : ((ii & 3) == 2) ? h2 : h3;
        float hv = __shfl(hsrc, ii >> 2, 64);
        acc = fmaf(hv, Wcol[ii * 20], acc);
    }
    if (lane < 32) z2[(size_t)n * 32 + lane] = __float2half(doL ? acc : 0.f);
    if (doR) r2[(size_t)n * 20 + (lane - 32)] = acc;
}

// ---- Layer 2: wave-per-node gather, combine, norm, W_out, softmax ----
__global__ __launch_bounds__(256) void k_agg2(
    const int* __restrict__ row_ptr, const int* __restrict__ eid,
    const __half* __restrict__ z2, const float* __restrict__ r2,
    const float* __restrict__ bias2, const float* __restrict__ Wout,
    const float* __restrict__ bout,
    float* __restrict__ out, int n_nodes)
{
    int n = (blockIdx.x * 256 + threadIdx.x) >> 6;
    if (n >= n_nodes) return;
    int lane = threadIdx.x & 63;
    int s = lane >> 3;
    int q = lane & 7;
    int beg = row_ptr[n], end = row_ptr[n + 1];
    int m = end - beg;
    int K = m >> 3;
    const char* zb = (const char*)z2;
    int boff = q << 3;
    float A0=0,A1=0,A2=0,A3=0, B0=0,B1=0,B2=0,B3=0;
    float C0=0,C1=0,C2=0,C3=0, D0=0,D1=0,D2=0,D3=0;
    int base = beg + s;
    int k = 0;
    for (; k + 4 <= K; k += 4) {
        int e0 = eid[base + 8*k];
        int e1 = eid[base + 8*k + 8];
        int e2 = eid[base + 8*k + 16];
        int e3 = eid[base + 8*k + 24];
        uint2 g0 = *reinterpret_cast<const uint2*>(zb + ((size_t)e0 << 6) + boff);
        uint2 g1 = *reinterpret_cast<const uint2*>(zb + ((size_t)e1 << 6) + boff);
        uint2 g2 = *reinterpret_cast<const uint2*>(zb + ((size_t)e2 << 6) + boff);
        uint2 g3 = *reinterpret_cast<const uint2*>(zb + ((size_t)e3 << 6) + boff);
        acc4(g0, A0, A1, A2, A3);
        acc4(g1, B0, B1, B2, B3);
        acc4(g2, C0, C1, C2, C3);
        acc4(g3, D0, D1, D2, D3);
    }
    for (; k < K; ++k) {
        int e = eid[base + 8*k];
        uint2 g = *reinterpret_cast<const uint2*>(zb + ((size_t)e << 6) + boff);
        acc4(g, A0, A1, A2, A3);
    }
    if (s < (m & 7)) {
        int e = eid[beg + 8*K + s];
        uint2 g = *reinterpret_cast<const uint2*>(zb + ((size_t)e << 6) + boff);
        acc4(g, B0, B1, B2, B3);
    }
    float v0 = (A0 + B0) + (C0 + D0);
    float v1 = (A1 + B1) + (C1 + D1);
    float v2 = (A2 + B2) + (C2 + D2);
    float v3 = (A3 + B3) + (C3 + D3);
#pragma unroll
    for (int off = 8; off < 64; off <<= 1) {
        v0 += __shfl_xor(v0, off, 64);
        v1 += __shfl_xor(v1, off, 64);
        v2 += __shfl_xor(v2, off, 64);
        v3 += __shfl_xor(v3, off, 64);
    }
    float inv = 1.0f / fmaxf((float)m, 1.0f);
    float w0 = 0.f, w1 = 0.f, w2 = 0.f, w3 = 0.f;
    if (q < 5) {     // channels 4q..4q+3 < 20
        int ch0 = q << 2;
        float4 rs = *reinterpret_cast<const float4*>(r2 + (size_t)n * 20 + ch0);
        float4 bs = *reinterpret_cast<const float4*>(bias2 + ch0);
        w0 = fmaf(v0, inv, bs.x + rs.x);
        w1 = fmaf(v1, inv, bs.y + rs.y);
        w2 = fmaf(v2, inv, bs.z + rs.z);
        w3 = fmaf(v3, inv, bs.w + rs.w);
    }
    float ss = w0*w0 + w1*w1 + w2*w2 + w3*w3;
#pragma unroll
    for (int off = 1; off < 8; off <<= 1) ss += __shfl_xor(ss, off, 64);
    float innrm = 1.0f / fmaxf(sqrtf(ss), 1e-12f);
    float o0 = w0 * innrm, o1 = w1 * innrm, o2 = w2 * innrm, o3 = w3 * innrm;
    // logits on lanes 0..9
    float lacc = (lane < 10) ? bout[lane] : 0.f;
#pragma unroll
    for (int ii = 0; ii < 20; ++ii) {
        float osrc = ((ii & 3) == 0) ? o0 : ((ii & 3) == 1) ? o1
                   : ((ii & 3) == 2) ? o2 : o3;
        float ov = __shfl(osrc, ii >> 2, 64);
        if (lane < 10) lacc = fmaf(ov, Wout[ii * 10 + lane], lacc);
    }
    float lm = (lane < 10) ? lacc : -1e30f;
#pragma unroll
    for (int off = 1; off < 16; off <<= 1) lm = fmaxf(lm, __shfl_xor(lm, off, 64));
    float ex = (lane < 10) ? expf(lacc - lm) : 0.f;
    float es = ex;
#pragma unroll
    for (int off = 1; off < 16; off <<= 1) es += __shfl_xor(es, off, 64);
    if (lane < 10) out[(size_t)n * 10 + lane] = ex / es;
}

extern "C" void kernel_launch(void* const* d_in, const int* in_sizes, int n_in,
                              void* d_out, int out_size, void* d_ws, size_t ws_size,
                              hipStream_t stream)
{
    const float* x    = (const float*)d_in[0];
    const int*   ei   = (const int*)d_in[1];
    const float* W1l  = (const float*)d_in[2];
    const float* b1   = (const float*)d_in[3];
    const float* W1r  = (const float*)d_in[4];
    const float* W2l  = (const float*)d_in[5];
    const float* b2   = (const float*)d_in[6];
    const float* W2r  = (const float*)d_in[7];
    const float* Wout = (const float*)d_in[8];
    const float* bout = (const float*)d_in[9];
    float* out = (float*)d_out;

    int n_nodes = in_sizes[0] / 128;
    int n_edges = in_sizes[1] / 2;
    const int* src = ei;
    const int* dst = ei + n_edges;

    int nb = (n_nodes + BS_NODES - 1) / BS_NODES;   // 782 (<= 1024)
    double mean = (double)n_edges / nb;
    int capb = (int)(mean + 8.0 * sqrt(mean) + 64.0);
    capb = (capb + 63) & ~63;

    // workspace layout
    int* bcursor = (int*)d_ws;                          // nb
    int* bbase   = bcursor + ((nb + 2 + 3) & ~3);       // nb
    int* row_ptr = bbase + ((nb + 3) & ~3);             // n_nodes+1
    int* eid     = row_ptr + (((n_nodes + 1) + 3) & ~3);// n_edges
    int* pairs   = eid + (((size_t)n_edges + 3) & ~(size_t)3);  // nb*capb

    // fp16 gather tables; y1 aliases pairs (pairs dead before k_lin1 runs)
    __half* y1 = (__half*)pairs;                        // N*32 halfs (64B rows)
    float*  r1 = (float*)(y1 + (size_t)n_nodes * 32);   // N*32 f32
    __half* z2 = (__half*)(r1 + (size_t)n_nodes * 32);  // N*32 halfs (20 used)
    float*  r2 = (float*)(z2 + (size_t)n_nodes * 32);   // N*20 f32

    int nb_part = (n_edges + PART_TILE - 1) / PART_TILE;
    int nb_node = (n_nodes + 255) / 256;
    int nb_wave = (n_nodes + 3) / 4;     // 4 waves (nodes) per 256-block

    k_binit<<<(nb + 255) / 256, 256, 0, stream>>>(bcursor, nb, capb);
    k_part<<<nb_part, 256, 0, stream>>>(src, dst, bcursor, pairs, n_edges, nb);
    k_bscan<<<1, 1024, 0, stream>>>(bcursor, bbase, row_ptr, nb, capb, n_nodes);
    k_bfill<<<nb, 256, 0, stream>>>(pairs, bcursor, bbase, row_ptr, eid, capb, n_nodes);
    k_lin1<<<nb_node, 256, 0, stream>>>(x, W1l, W1r, y1, r1, n_nodes);
    k_agg1<<<nb_wave, 256, 0, stream>>>(row_ptr, eid, y1, r1, b1, W2l, W2r, z2, r2, n_nodes);
    k_agg2<<<nb_wave, 256, 0, stream>>>(row_ptr, eid, z2, r2, b2, Wout, bout, out, n_nodes);
}